// Round 1
// baseline (332.922 us; speedup 1.0000x reference)
//
#include <hip/hip_runtime.h>

#define LAMBDA_COOR 5.0f
#define LAMBDA_NOOBJ 0.5f

// Each "group" = 4 cells = 20 contiguous floats = 5 aligned float4 loads.
__global__ __launch_bounds__(256) void yolo_loss_kernel(
    const float* __restrict__ outp, const float* __restrict__ tgt,
    float* __restrict__ loss, int n_groups, float inv_b)
{
    int tid = blockIdx.x * blockDim.x + threadIdx.x;
    int stride = gridDim.x * blockDim.x;
    float acc = 0.0f;

    for (int g = tid; g < n_groups; g += stride) {
        const float4* o4 = (const float4*)(outp + (size_t)g * 20);
        const float4* t4 = (const float4*)(tgt + (size_t)g * 20);
        float o[20], t[20];
        #pragma unroll
        for (int i = 0; i < 5; ++i) {
            float4 a = o4[i];
            float4 b = t4[i];
            o[4*i+0] = a.x; o[4*i+1] = a.y; o[4*i+2] = a.z; o[4*i+3] = a.w;
            t[4*i+0] = b.x; t[4*i+1] = b.y; t[4*i+2] = b.z; t[4*i+3] = b.w;
        }
        #pragma unroll
        for (int c = 0; c < 4; ++c) {
            const float* oc = o + 5*c;
            const float* tc = t + 5*c;
            float conf_p = oc[0];
            float coord = 0.0f;
            #pragma unroll
            for (int k = 1; k < 5; ++k) {
                float d = oc[k] - tc[k];
                coord += d * d;
            }
            float obj   = LAMBDA_COOR * coord + (conf_p - 1.0f) * (conf_p - 1.0f);
            float noobj = LAMBDA_NOOBJ * conf_p * conf_p;
            acc += (tc[0] > 0.0f) ? obj : noobj;
        }
    }

    // 64-lane wave reduction
    #pragma unroll
    for (int off = 32; off > 0; off >>= 1)
        acc += __shfl_down(acc, off, 64);

    __shared__ float wave_sums[4];  // 256 threads / 64 lanes
    int lane = threadIdx.x & 63;
    int wid  = threadIdx.x >> 6;
    if (lane == 0) wave_sums[wid] = acc;
    __syncthreads();

    if (threadIdx.x == 0) {
        float s = wave_sums[0] + wave_sums[1] + wave_sums[2] + wave_sums[3];
        atomicAdd(loss, s * inv_b);
    }
}

extern "C" void kernel_launch(void* const* d_in, const int* in_sizes, int n_in,
                              void* d_out, int out_size, void* d_ws, size_t ws_size,
                              hipStream_t stream) {
    const float* outputs = (const float*)d_in[0];
    const float* targets = (const float*)d_in[1];
    float* loss = (float*)d_out;

    const int n_elems  = in_sizes[0];          // 128*256*256*5 = 41,943,040
    const int n_groups = n_elems / 20;         // 2,097,152 groups of 4 cells
    const float inv_b  = 1.0f / 128.0f;        // B = 128

    // d_out is poisoned to 0xAA before every timed launch; zero it on-stream.
    hipMemsetAsync(d_out, 0, sizeof(float), stream);

    const int threads = 256;
    const int blocks  = 2048;                  // grid-stride: 4 groups/thread
    yolo_loss_kernel<<<blocks, threads, 0, stream>>>(
        outputs, targets, loss, n_groups, inv_b);
}